// Round 9
// baseline (106.533 us; speedup 1.0000x reference)
//
#include <hip/hip_runtime.h>
#include <stdint.h>

#define INDIM   1024
#define OUTDIM  1024
#define BM 128
#define BN 128
#define BK 64
#define KTILES (INDIM / BK)    // 16

typedef __attribute__((ext_vector_type(8))) short  short8;   // 8 bf16 (4 VGPRs)
typedef __attribute__((ext_vector_type(4))) float  floatx4;  // MFMA acc

// ---------------- build dense W^T (fp32, handles duplicate (i,o) by add) ----
__global__ void k_scatter_w(const int* __restrict__ ind_in, const int* __restrict__ ind_out,
                            const float* __restrict__ w, float* __restrict__ W32T, int nnz) {
    int k = blockIdx.x * 256 + threadIdx.x;
    if (k < nnz)
        atomicAdd(&W32T[(size_t)ind_out[k] * INDIM + ind_in[k]], w[k]);
}

// fp32 pair -> packed bf16x2 (RNE)
__device__ __forceinline__ uint32_t bf16pack(float x, float y) {
    uint32_t ux = __float_as_uint(x);
    ux = ((ux + 0x7FFFu + ((ux >> 16) & 1u)) >> 16) & 0xFFFFu;   // low  = x
    uint32_t uy = __float_as_uint(y);
    uy = (uy + 0x7FFFu + ((uy >> 16) & 1u)) & 0xFFFF0000u;       // high = y
    return ux | uy;
}

__device__ __forceinline__ uint4 pack8(float4 a, float4 b) {
    return make_uint4(bf16pack(a.x, a.y), bf16pack(a.z, a.w),
                      bf16pack(b.x, b.y), bf16pack(b.z, b.w));
}

// W fp32 -> bf16 (6 MB traffic, ~1.5 us). B is reused 32x by the gemm, so
// paying once to halve its resident size (2 MB, fits per-XCD L2) wins;
// A stays fp32 and is packed in the gemm's staging path (read ~once).
__global__ void k_convert_w(const float4* __restrict__ Wt, uint2* __restrict__ W16, int n4) {
    int i = blockIdx.x * 256 + threadIdx.x;
    if (i < n4) {
        float4 v = Wt[i];
        W16[i] = make_uint2(bf16pack(v.x, v.y), bf16pack(v.z, v.w));
    }
}

// ---------------- bf16 MFMA GEMM: C = A(fp32) * W16T^T + bias --------------
// R9: 128x128x64 tile, 512 threads (8 waves), grid 256 = 2 blocks/CU =
// 16 waves/CU (same TLP as R7's winner; R6's failure was 4 waves/CU).
// Halves L2 operand re-reads vs 64x64 (1/BM+1/BN: 1/32 -> 1/64). Mixed
// staging: A fp32 + fused bf16pack, B pre-converted bf16. XOR chunk swizzle
// (R6/R7 measured SQ_LDS_BANK_CONFLICT = 0). Nontemporal C stores keep the
// write stream from evicting the per-XCD hot set (A band 2 MB + W16T 2 MB).
// Verified layouts (guide §3): A-frag m=lane&15,k=quad*8+j; B-frag n=lane&15;
// C/D col=lane&15,row=quad*4+r.
__global__ __launch_bounds__(512, 4) void k_gemm(
    const float* __restrict__ A32,    // [M][1024] fp32 row-major (input)
    const ushort* __restrict__ W16T,  // [1024 n][1024 k] bf16 row-major
    const float* __restrict__ bias,
    float* __restrict__ C, int M)
{
    __shared__ ushort lA[BM * BK];   // 16 KB
    __shared__ ushort lB[BN * BK];   // 16 KB

    const int t      = threadIdx.x;
    const int w      = t >> 6;
    const int L      = t & 63;
    const int lane15 = L & 15;
    const int lane7  = L & 7;
    const int quad   = L >> 4;
    const int wm     = w >> 1;        // 0..3 : 32-row band
    const int wn     = w & 1;         // 0..1 : 64-col band

    // XCD swizzle (XCD = bid&7 round-robin, 256 blocks): XCD x owns m-tiles
    // {4x..4x+3} x all 8 n-tiles -> per-XCD hot set = 2 MB A (fp32 band) +
    // 2 MB W16T. Heuristic only; correctness unaffected.
    const int bid = blockIdx.x;
    int bm0, bn0;
    if (gridDim.x == 256) {
        bm0 = ((bid & 7) * 4 + (bid >> 6)) * BM;
        bn0 = ((bid >> 3) & 7) * BN;
    } else {
        bm0 = (bid / (OUTDIM / BN)) * BM;
        bn0 = (bid % (OUTDIM / BN)) * BN;
    }

    // staging: 1024 16B-chunks per operand per iter; thread t owns chunks
    // c0 = t, c1 = t+512 of each. row = c>>3 (c1: +64, same row&7), slot =
    // c&7, stored global chunk = slot ^ (row&7) -> one j8 per thread.
    const int srow = t >> 3;                       // 0..63
    const int j8   = (t & 7) ^ (srow & 7);

    const float*  Abase = A32  + (size_t)bm0 * INDIM;
    const ushort* Bbase = W16T + (size_t)bn0 * INDIM;

    floatx4 acc[2][4] = {};

    for (int kt = 0; kt < KTILES; ++kt) {
        const int gcol = kt * BK + j8 * 8;
        const float* pa0 = Abase + (size_t)srow        * INDIM + gcol;
        const float* pa1 = Abase + (size_t)(srow + 64) * INDIM + gcol;
        uint4 va0 = pack8(*(const float4*)pa0, *(const float4*)(pa0 + 4));
        uint4 va1 = pack8(*(const float4*)pa1, *(const float4*)(pa1 + 4));
        uint4 vb0 = *(const uint4*)(Bbase + (size_t)srow        * INDIM + gcol);
        uint4 vb1 = *(const uint4*)(Bbase + (size_t)(srow + 64) * INDIM + gcol);
        __syncthreads();                 // previous iter done reading LDS
        *(uint4*)(lA + (size_t)t * 8)         = va0;
        *(uint4*)(lA + (size_t)(t + 512) * 8) = va1;
        *(uint4*)(lB + (size_t)t * 8)         = vb0;
        *(uint4*)(lB + (size_t)(t + 512) * 8) = vb1;
        __syncthreads();                 // writes visible

        #pragma unroll
        for (int ks = 0; ks < 2; ++ks) {
            const int koff = (((ks * 4 + quad) ^ lane7) * 8);
            short8 af[2], bf[4];
            #pragma unroll
            for (int tm = 0; tm < 2; ++tm)
                af[tm] = *(const short8*)(lA + (wm * 32 + tm * 16 + lane15) * 64 + koff);
            #pragma unroll
            for (int tn = 0; tn < 4; ++tn)
                bf[tn] = *(const short8*)(lB + (wn * 64 + tn * 16 + lane15) * 64 + koff);
            #pragma unroll
            for (int tm = 0; tm < 2; ++tm)
                #pragma unroll
                for (int tn = 0; tn < 4; ++tn)
                    acc[tm][tn] = __builtin_amdgcn_mfma_f32_16x16x32_bf16(
                        af[tm], bf[tn], acc[tm][tn], 0, 0, 0);
        }
    }

    // ---- epilogue: bias + nontemporal store (C never re-read) ----
    #pragma unroll
    for (int tm = 0; tm < 2; ++tm) {
        #pragma unroll
        for (int tn = 0; tn < 4; ++tn) {
            const int col = bn0 + wn * 64 + tn * 16 + lane15;
            const float bv = bias[col];
            #pragma unroll
            for (int r = 0; r < 4; ++r) {
                const int row = bm0 + wm * 32 + tm * 16 + quad * 4 + r;
                __builtin_nontemporal_store(acc[tm][tn][r] + bv,
                                            &C[(size_t)row * OUTDIM + col]);
            }
        }
    }
}

// ---------------- launcher ----------------
extern "C" void kernel_launch(void* const* d_in, const int* in_sizes, int n_in,
                              void* d_out, int out_size, void* d_ws, size_t ws_size,
                              hipStream_t stream) {
    const float* input  = (const float*)d_in[0];
    const float* weight = (const float*)d_in[1];
    const float* bias   = (const float*)d_in[2];
    const int*   ind_in  = (const int*)d_in[3];
    const int*   ind_out = (const int*)d_in[4];
    float* out = (float*)d_out;

    const int nnz = in_sizes[1];
    const int M   = out_size / OUTDIM;      // 4096

    char* ws = (char*)d_ws;
    float*  W32T = (float*)ws;                    // 4 MB @ 0
    ushort* W16T = (ushort*)(ws + (4u << 20));    // 2 MB @ 4 MB

    (void)hipMemsetAsync(W32T, 0, (size_t)OUTDIM * INDIM * sizeof(float), stream);
    k_scatter_w<<<(nnz + 255) / 256, 256, 0, stream>>>(ind_in, ind_out, weight, W32T, nnz);
    k_convert_w<<<OUTDIM * INDIM / 4 / 256, 256, 0, stream>>>(
        (const float4*)W32T, (uint2*)W16T, OUTDIM * INDIM / 4);
    k_gemm<<<(M / BM) * (OUTDIM / BN), 512, 0, stream>>>(input, W16T, bias, out, M);
}